// Round 5
// baseline (571.501 us; speedup 1.0000x reference)
//
#include <hip/hip_runtime.h>
#include <cstdint>
#include <cstddef>

// FullLinearAttention — fused pipeline, 256x256/BK=32 ring-3 counted-vmcnt
// GEMM core, 8 waves/block (512 thr), 96KB LDS, 1 block/CU (m201 regime).
//   K0  cvt:     xb=bf16(x) -> O[0,64M); wbq -> O[64M,70M); wbo -> W1[0,2M)
//   K1  kvfold:  per (rt,hp) block: [256 x (k64|k64|v64|v64)] for heads
//                2hp,2hp+1, elu on k, in-LDS fold -> Pp O[72M,104M) + KsP
//   K2  reduce:  32 row-tile partials -> kvb,ksb (bf16) in W1[2M,2.51M)
//   K3  qattn:   q GEMM tile (wave = one of 4 heads), elu, LDS round-trip,
//                (q@kv)/max(q.ksum,1e-6) -> attn bf16 A[0,64M)
//   K4  out:     attn@wbo^T -> f32 directly into d_out O[0,128M)

typedef __bf16 bf16;
typedef __bf16 bf16x8 __attribute__((ext_vector_type(8)));
typedef float  f32x4  __attribute__((ext_vector_type(4)));

#define MFMA(a, b, c) __builtin_amdgcn_mfma_f32_16x16x32_bf16((a), (b), (c), 0, 0, 0)

__device__ __forceinline__ void gld_lds16(const bf16* g, bf16* l) {
  __builtin_amdgcn_global_load_lds(
      (const __attribute__((address_space(1))) void*)g,
      (__attribute__((address_space(3))) void*)l, 16, 0, 0);
}

// ---------------------------------------------------------------- convert ---
__global__ __launch_bounds__(256) void cvt_bf16(const float* __restrict__ src,
                                                bf16* __restrict__ dst, int n8) {
  const int stride = gridDim.x * 256;
  for (int i = blockIdx.x * 256 + threadIdx.x; i < n8; i += stride) {
    const float* p = src + (size_t)i * 8;
    f32x4 a = *(const f32x4*)p;
    f32x4 b = *(const f32x4*)(p + 4);
    bf16x8 r;
    r[0] = (bf16)a[0]; r[1] = (bf16)a[1]; r[2] = (bf16)a[2]; r[3] = (bf16)a[3];
    r[4] = (bf16)b[0]; r[5] = (bf16)b[1]; r[6] = (bf16)b[2]; r[7] = (bf16)b[3];
    *(bf16x8*)(dst + (size_t)i * 8) = r;
  }
}

// --------------------------------------------------------- shared K-loop ----
// C[256,256] += A[256,1024] @ B[256rows,1024]^T.  BK=32, ring-3 slabs of
// 16384 elems (A 8192 | B 8192) in smem[49152].  8 waves: wm=w>>2 (128 rows),
// wn=w&3 (64 cols); per-wave 128x64.  Granule swizzle col^=(row>>1)&3 via
// pre-swizzled global source (LDS dest linear).  Stage tile t+2 during t's
// two phases (A in phase0, B in phase1; 4 loads/tile); vmcnt(4) at tile top.
template<int SLAB, bool ST, bool LAST>
__device__ __forceinline__ void ktile8(
    const bf16* vA, const bf16* vB, bf16* sAd, bf16* sBd,
    const bf16* gA, const bf16* gB0, const bf16* gB1,
    f32x4 (&acc)[8][4]) {
  constexpr int NS = (SLAB + 2) % 3;
  constexpr int CB = SLAB * 16384;
  if (!LAST) asm volatile("s_waitcnt vmcnt(4)" ::: "memory");
  else       asm volatile("s_waitcnt vmcnt(0)" ::: "memory");
  __builtin_amdgcn_s_barrier();
  __builtin_amdgcn_sched_barrier(0);

  bf16x8 bv[4], af[4];
#pragma unroll
  for (int nf = 0; nf < 4; ++nf)
    bv[nf] = *(const bf16x8*)&vB[CB + nf * 512];
#pragma unroll
  for (int i = 0; i < 4; ++i)
    af[i] = *(const bf16x8*)&vA[CB + i * 512];
  if (ST) {
    gld_lds16(gA,          sAd + NS * 16384);
    gld_lds16(gA + 131072, sAd + NS * 16384 + 4096);
  }
  __builtin_amdgcn_s_barrier();
  asm volatile("s_waitcnt lgkmcnt(0)" ::: "memory");
  __builtin_amdgcn_sched_barrier(0);
  __builtin_amdgcn_s_setprio(1);
#pragma unroll
  for (int i = 0; i < 4; ++i)
#pragma unroll
    for (int nf = 0; nf < 4; ++nf)
      acc[i][nf] = MFMA(af[i], bv[nf], acc[i][nf]);
  __builtin_amdgcn_s_setprio(0);
  __builtin_amdgcn_s_barrier();

#pragma unroll
  for (int i = 0; i < 4; ++i)
    af[i] = *(const bf16x8*)&vA[CB + 2048 + i * 512];
  if (ST) {
    gld_lds16(gB0, sBd + NS * 16384);
    gld_lds16(gB1, sBd + NS * 16384 + 4096);
  }
  __builtin_amdgcn_s_barrier();
  asm volatile("s_waitcnt lgkmcnt(0)" ::: "memory");
  __builtin_amdgcn_sched_barrier(0);
  __builtin_amdgcn_s_setprio(1);
#pragma unroll
  for (int i = 0; i < 4; ++i)
#pragma unroll
    for (int nf = 0; nf < 4; ++nf)
      acc[4 + i][nf] = MFMA(af[i], bv[nf], acc[4 + i][nf]);
  __builtin_amdgcn_s_setprio(0);
  __builtin_amdgcn_s_barrier();
}

__device__ __forceinline__ void kloop8(
    bf16* smem, const bf16* pA, const bf16* pB0, const bf16* pB1,
    int tid, const bf16* vA, const bf16* vB, f32x4 (&acc)[8][4]) {
  bf16* sAd = smem + tid * 8;
  bf16* sBd = smem + 8192 + tid * 8;
#pragma unroll
  for (int t = 0; t < 2; ++t) {
    const int kk = t * 32;
    gld_lds16(pA + kk,          sAd + t * 16384);
    gld_lds16(pA + kk + 131072, sAd + t * 16384 + 4096);
    gld_lds16(pB0 + kk,         sBd + t * 16384);
    gld_lds16(pB1 + kk,         sBd + t * 16384 + 4096);
  }
#pragma unroll
  for (int c = 0; c < 10; ++c) {
    const int o = 64 + c * 96;  // K-elem offset of tile 3c+2
    ktile8<0, true, false>(vA, vB, sAd, sBd, pA + o,      pB0 + o,      pB1 + o,      acc);
    ktile8<1, true, false>(vA, vB, sAd, sBd, pA + o + 32, pB0 + o + 32, pB1 + o + 32, acc);
    ktile8<2, true, false>(vA, vB, sAd, sBd, pA + o + 64, pB0 + o + 64, pB1 + o + 64, acc);
  }
  ktile8<0, false, false>(vA, vB, sAd, sBd, pA, pB0, pB1, acc);
  ktile8<1, false, true >(vA, vB, sAd, sBd, pA, pB0, pB1, acc);
}

// ---------------------------------------------------------------- kvfold ----
// grid 1024 = 128 rt x 8 hp (hp fastest). Cols: [k(2hp)|k(2hp+1)|v(2hp)|
// v(2hp+1)]. Wave wn owns exactly one (type,head). Fold -> 2 partials/block.
__global__ __launch_bounds__(512, 2) void gemm_kvfold(
    const bf16* __restrict__ xb, const bf16* __restrict__ wbq,
    float* __restrict__ Pp, float* __restrict__ KsP) {
  __shared__ __align__(16) bf16 smem[49152];
  const int tid = threadIdx.x;
  const int w = tid >> 6, lane = tid & 63;
  const int grp = lane >> 4, mlane = lane & 15;
  const int wm = w >> 2, wn = w & 3;

  int bid = (int)blockIdx.x;
  const int cpx = (int)gridDim.x >> 3;
  bid = (bid & 7) * cpx + (bid >> 3);
  const int hp = bid & 7, rt = bid >> 3;
  const int rowA0 = rt * 256;

  const int lrr = tid >> 2;
  const int lcs = (tid & 3) ^ ((tid >> 3) & 3);
  const bf16* pA  = xb + (size_t)(rowA0 + lrr) * 1024 + lcs * 8;
  const bf16* pB0 = wbq + (size_t)(1024 + hp * 128 + lrr) * 1024 + lcs * 8;
  const bf16* pB1 = wbq + (size_t)(2048 + hp * 128 + lrr) * 1024 + lcs * 8;
  const int cgo = (grp ^ ((mlane >> 1) & 3)) * 8;
  const bf16* vA = smem + (wm * 128 + mlane) * 32 + cgo;
  const bf16* vB = smem + 8192 + (wn * 64 + mlane) * 32 + cgo;

  const f32x4 zero = {0.f, 0.f, 0.f, 0.f};
  f32x4 acc[8][4];
#pragma unroll
  for (int i = 0; i < 8; ++i)
#pragma unroll
    for (int j = 0; j < 4; ++j) acc[i][j] = zero;

  kloop8(smem, pA, pB0, pB1, tid, vA, vB, acc);

  bf16* Kt = smem;            // [256][68]
  bf16* Vt = smem + 17408;    // [256][68]
  float* P4 = (float*)smem;   // [4][4096] (reuse, after fold reads)
  float* K4 = (float*)((char*)smem + 65536);  // [4][64]
  bf16x8 ones;
#pragma unroll
  for (int jj = 0; jj < 8; ++jj) ones[jj] = (bf16)1.0f;

#pragma unroll
  for (int h = 0; h < 2; ++h) {
    __syncthreads();
    if (wn == h || wn == 2 + h) {
      const bool isk = (wn == h);
      bf16* T = isk ? Kt : Vt;
#pragma unroll
      for (int mf = 0; mf < 8; ++mf)
#pragma unroll
        for (int nf = 0; nf < 4; ++nf)
#pragma unroll
          for (int r = 0; r < 4; ++r) {
            float v = acc[mf][nf][r];
            if (isk) v = (v > 0.f) ? (v + 1.f) : __expf(v);
            T[(wm * 128 + mf * 16 + grp * 4 + r) * 68 + nf * 16 + mlane] = (bf16)v;
          }
    }
    __syncthreads();

    f32x4 akv[4][4], a5[4];
#pragma unroll
    for (int i = 0; i < 4; ++i) {
      a5[i] = zero;
#pragma unroll
      for (int j = 0; j < 4; ++j) akv[i][j] = zero;
    }
    {
      const int sw = w * 32;
      bf16x8 av[4], bk[4];
#pragma unroll
      for (int jj = 0; jj < 8; ++jj) {
        const bf16* vr = &Vt[(sw + grp * 8 + jj) * 68];
        const bf16* kr = &Kt[(sw + grp * 8 + jj) * 68];
#pragma unroll
        for (int i = 0; i < 4; ++i) av[i][jj] = vr[i * 16 + mlane];
#pragma unroll
        for (int j = 0; j < 4; ++j) bk[j][jj] = kr[j * 16 + mlane];
      }
#pragma unroll
      for (int i = 0; i < 4; ++i)
#pragma unroll
        for (int j = 0; j < 4; ++j) akv[i][j] = MFMA(av[i], bk[j], akv[i][j]);
#pragma unroll
      for (int j = 0; j < 4; ++j) a5[j] = MFMA(ones, bk[j], a5[j]);
    }
    __syncthreads();  // done reading Kt/Vt; P4/K4 region now free

    // 8 -> 4
    if (w >= 4) {
#pragma unroll
      for (int i = 0; i < 4; ++i)
#pragma unroll
        for (int j = 0; j < 4; ++j)
#pragma unroll
          for (int r = 0; r < 4; ++r)
            P4[(w - 4) * 4096 + (i * 16 + grp * 4 + r) * 64 + j * 16 + mlane] =
                akv[i][j][r];
      if (grp == 0) {
#pragma unroll
        for (int j = 0; j < 4; ++j) K4[(w - 4) * 64 + j * 16 + mlane] = a5[j][0];
      }
    }
    __syncthreads();
    if (w < 4) {
#pragma unroll
      for (int i = 0; i < 4; ++i)
#pragma unroll
        for (int j = 0; j < 4; ++j)
#pragma unroll
          for (int r = 0; r < 4; ++r)
            akv[i][j][r] += P4[w * 4096 + (i * 16 + grp * 4 + r) * 64 + j * 16 + mlane];
      if (grp == 0) {
#pragma unroll
        for (int j = 0; j < 4; ++j) a5[j][0] += K4[w * 64 + j * 16 + mlane];
      }
    }
    __syncthreads();
    // 4 -> 2
    if (w == 2 || w == 3) {
#pragma unroll
      for (int i = 0; i < 4; ++i)
#pragma unroll
        for (int j = 0; j < 4; ++j)
#pragma unroll
          for (int r = 0; r < 4; ++r)
            P4[(w - 2) * 4096 + (i * 16 + grp * 4 + r) * 64 + j * 16 + mlane] =
                akv[i][j][r];
      if (grp == 0) {
#pragma unroll
        for (int j = 0; j < 4; ++j) K4[(w - 2) * 64 + j * 16 + mlane] = a5[j][0];
      }
    }
    __syncthreads();
    if (w < 2) {
#pragma unroll
      for (int i = 0; i < 4; ++i)
#pragma unroll
        for (int j = 0; j < 4; ++j)
#pragma unroll
          for (int r = 0; r < 4; ++r)
            akv[i][j][r] += P4[w * 4096 + (i * 16 + grp * 4 + r) * 64 + j * 16 + mlane];
      if (grp == 0) {
#pragma unroll
        for (int j = 0; j < 4; ++j) a5[j][0] += K4[w * 64 + j * 16 + mlane];
      }
    }
    __syncthreads();
    // 2 -> 1
    if (w == 1) {
#pragma unroll
      for (int i = 0; i < 4; ++i)
#pragma unroll
        for (int j = 0; j < 4; ++j)
#pragma unroll
          for (int r = 0; r < 4; ++r)
            P4[4096 + (i * 16 + grp * 4 + r) * 64 + j * 16 + mlane] = akv[i][j][r];
      if (grp == 0) {
#pragma unroll
        for (int j = 0; j < 4; ++j) K4[64 + j * 16 + mlane] = a5[j][0];
      }
    }
    __syncthreads();
    if (w == 0) {
      const int widx = rt * 16 + hp * 2 + h;
      float* pw = Pp + (size_t)widx * 4096;
#pragma unroll
      for (int i = 0; i < 4; ++i)
#pragma unroll
        for (int j = 0; j < 4; ++j)
#pragma unroll
          for (int r = 0; r < 4; ++r)
            pw[(i * 16 + grp * 4 + r) * 64 + j * 16 + mlane] =
                akv[i][j][r] +
                P4[4096 + (i * 16 + grp * 4 + r) * 64 + j * 16 + mlane];
      if (grp == 0) {
#pragma unroll
        for (int j = 0; j < 4; ++j)
          KsP[(size_t)widx * 64 + j * 16 + mlane] =
              a5[j][0] + K4[64 + j * 16 + mlane];
      }
    }
  }
}

// ----------------------------------------------------------------- reduce ---
__global__ __launch_bounds__(256) void reduce_kv2(
    const float* __restrict__ Pp, const float* __restrict__ KsP,
    bf16* __restrict__ kvb, bf16* __restrict__ ksb) {
  const int bh = blockIdx.x, y = blockIdx.y, tid = threadIdx.x;
  const int b = bh >> 4, h = bh & 15;
  if (y < 16) {
    const int o = y * 256 + tid;
    float s = 0.f;
#pragma unroll
    for (int i = 0; i < 32; ++i)
      s += Pp[(size_t)((b * 32 + i) * 16 + h) * 4096 + o];
    kvb[(size_t)bh * 4096 + o] = (bf16)s;
  } else if (tid < 64) {
    float s = 0.f;
#pragma unroll
    for (int i = 0; i < 32; ++i)
      s += KsP[(size_t)((b * 32 + i) * 16 + h) * 64 + tid];
    ksb[bh * 64 + tid] = (bf16)s;
  }
}

// ----------------------------------------------------------------- qattn ----
// grid 512 = 128 rt x 4 ct (ct fastest). Wave = one head (head = ct*4+wn).
// Epilogue: elu->bf16->Qs (XOR-swizzled [64][64])->q@kv + normalizer -> attn.
__global__ __launch_bounds__(512, 2) void gemm_qattn(
    const bf16* __restrict__ xb, const bf16* __restrict__ wbq,
    const bf16* __restrict__ kvb, const bf16* __restrict__ ksb,
    bf16* __restrict__ attn) {
  __shared__ __align__(16) bf16 smem[49152];
  const int tid = threadIdx.x;
  const int w = tid >> 6, lane = tid & 63;
  const int grp = lane >> 4, mlane = lane & 15;
  const int wm = w >> 2, wn = w & 3;

  int bid = (int)blockIdx.x;
  const int cpx = (int)gridDim.x >> 3;
  bid = (bid & 7) * cpx + (bid >> 3);
  const int ct = bid & 3, rt = bid >> 2;
  const int rowA0 = rt * 256;

  const int lrr = tid >> 2;
  const int lcs = (tid & 3) ^ ((tid >> 3) & 3);
  const bf16* pA  = xb + (size_t)(rowA0 + lrr) * 1024 + lcs * 8;
  const bf16* pB0 = wbq + (size_t)(ct * 256 + lrr) * 1024 + lcs * 8;
  const bf16* pB1 = pB0 + (size_t)128 * 1024;
  const int cgo = (grp ^ ((mlane >> 1) & 3)) * 8;
  const bf16* vA = smem + (wm * 128 + mlane) * 32 + cgo;
  const bf16* vB = smem + 8192 + (wn * 64 + mlane) * 32 + cgo;

  const f32x4 zero = {0.f, 0.f, 0.f, 0.f};
  f32x4 acc[8][4];
#pragma unroll
  for (int i = 0; i < 8; ++i)
#pragma unroll
    for (int j = 0; j < 4; ++j) acc[i][j] = zero;

  kloop8(smem, pA, pB0, pB1, tid, vA, vB, acc);

  // per-head kv / ksum fragments (tiny, L2-hot)
  const int head = ct * 4 + wn;
  const int bh = (rt >> 5) * 16 + head;
  bf16x8 bkv[2][4], b5v[2];
#pragma unroll
  for (int ks = 0; ks < 2; ++ks) {
#pragma unroll
    for (int nf = 0; nf < 4; ++nf)
      bkv[ks][nf] = *(const bf16x8*)&kvb[(size_t)bh * 4096 +
                                         (nf * 16 + mlane) * 64 + ks * 32 + grp * 8];
    b5v[ks] = *(const bf16x8*)&ksb[bh * 64 + ks * 32 + grp * 8];
  }

  // wave-private Qs [64][64] with 3-bit granule XOR swizzle (stride 128B)
  bf16* Qs = smem + w * 4096;
  const int swr = (mlane >> 1) & 7;
#pragma unroll
  for (int mh = 0; mh < 2; ++mh) {
#pragma unroll
    for (int i = 0; i < 4; ++i)
#pragma unroll
      for (int nf = 0; nf < 4; ++nf)
#pragma unroll
        for (int r = 0; r < 4; ++r) {
          float v = acc[mh * 4 + i][nf][r];
          v = (v > 0.f) ? (v + 1.f) : __expf(v);
          const int rw = i * 16 + grp * 4 + r;
          const int d = nf * 16 + mlane;
          Qs[rw * 64 + (((d >> 3) ^ ((rw >> 1) & 7)) << 3) + (d & 7)] = (bf16)v;
        }
    bf16x8 aq2[4][2];
#pragma unroll
    for (int i = 0; i < 4; ++i)
#pragma unroll
      for (int ks = 0; ks < 2; ++ks)
        aq2[i][ks] = *(const bf16x8*)&Qs[(i * 16 + mlane) * 64 +
                                         (((ks * 4 + grp) ^ swr) << 3)];
    f32x4 ao[4][4], a5q[4];
#pragma unroll
    for (int i = 0; i < 4; ++i) {
      a5q[i] = zero;
#pragma unroll
      for (int nf = 0; nf < 4; ++nf) ao[i][nf] = zero;
    }
#pragma unroll
    for (int ks = 0; ks < 2; ++ks)
#pragma unroll
      for (int i = 0; i < 4; ++i) {
#pragma unroll
        for (int nf = 0; nf < 4; ++nf)
          ao[i][nf] = MFMA(aq2[i][ks], bkv[ks][nf], ao[i][nf]);
        a5q[i] = MFMA(aq2[i][ks], b5v[ks], a5q[i]);
      }
#pragma unroll
    for (int i = 0; i < 4; ++i)
#pragma unroll
      for (int r = 0; r < 4; ++r) {
        const float inv = 1.0f / fmaxf(a5q[i][r], 1e-6f);
        bf16* op = attn + (size_t)(rowA0 + wm * 128 + mh * 64 + i * 16 +
                                   grp * 4 + r) * 1024 + head * 64;
#pragma unroll
        for (int nf = 0; nf < 4; ++nf)
          op[nf * 16 + mlane] = (bf16)(ao[i][nf][r] * inv);
      }
  }
}

// ------------------------------------------------------------------- out ----
// grid 512 = 128 rt x 4 ct. C f32 directly into d_out.
__global__ __launch_bounds__(512, 2) void gemm_out(
    const bf16* __restrict__ attn, const bf16* __restrict__ wbo,
    float* __restrict__ C) {
  __shared__ __align__(16) bf16 smem[49152];
  const int tid = threadIdx.x;
  const int w = tid >> 6, lane = tid & 63;
  const int grp = lane >> 4, mlane = lane & 15;
  const int wm = w >> 2, wn = w & 3;

  int bid = (int)blockIdx.x;
  const int cpx = (int)gridDim.x >> 3;
  bid = (bid & 7) * cpx + (bid >> 3);
  const int ct = bid & 3, rt = bid >> 2;
  const int rowA0 = rt * 256;

  const int lrr = tid >> 2;
  const int lcs = (tid & 3) ^ ((tid >> 3) & 3);
  const bf16* pA  = attn + (size_t)(rowA0 + lrr) * 1024 + lcs * 8;
  const bf16* pB0 = wbo + (size_t)(ct * 256 + lrr) * 1024 + lcs * 8;
  const bf16* pB1 = pB0 + (size_t)128 * 1024;
  const int cgo = (grp ^ ((mlane >> 1) & 3)) * 8;
  const bf16* vA = smem + (wm * 128 + mlane) * 32 + cgo;
  const bf16* vB = smem + 8192 + (wn * 64 + mlane) * 32 + cgo;

  const f32x4 zero = {0.f, 0.f, 0.f, 0.f};
  f32x4 acc[8][4];
#pragma unroll
  for (int i = 0; i < 8; ++i)
#pragma unroll
    for (int j = 0; j < 4; ++j) acc[i][j] = zero;

  kloop8(smem, pA, pB0, pB1, tid, vA, vB, acc);

#pragma unroll
  for (int mf = 0; mf < 8; ++mf)
#pragma unroll
    for (int nf = 0; nf < 4; ++nf) {
      float* cp = C + (size_t)(rowA0 + wm * 128 + mf * 16 + grp * 4) * 1024 +
                  ct * 256 + wn * 64 + nf * 16 + mlane;
#pragma unroll
      for (int r = 0; r < 4; ++r) cp[(size_t)r * 1024] = acc[mf][nf][r];
    }
}

// ----------------------------------------------------------------- launch ---
extern "C" void kernel_launch(void* const* d_in, const int* in_sizes, int n_in,
                              void* d_out, int out_size, void* d_ws, size_t ws_size,
                              hipStream_t stream) {
  const float* x     = (const float*)d_in[0];
  const float* w_qkv = (const float*)d_in[1];
  const float* w_out = (const float*)d_in[2];
  char* O  = (char*)d_out;
  char* A  = (char*)d_in[0];
  char* W1 = (char*)d_in[1];

  bf16*  xb   = (bf16*)O;                       // [32768][1024]
  bf16*  wbq  = (bf16*)(O + 67108864);          // [3072][1024]
  float* Pp   = (float*)(O + 75497472);         // [2048][4096] f32
  float* KsP  = (float*)(O + 109051904);        // [2048][64] f32
  bf16*  attn = (bf16*)A;                       // over x (dead after cvt)
  bf16*  wbo  = (bf16*)W1;                      // [1024][1024]
  bf16*  kvb  = (bf16*)(W1 + 2097152);          // [64][4096]
  bf16*  ksb  = (bf16*)(W1 + 2621440);          // [64][64]

  cvt_bf16<<<2048, 256, 0, stream>>>(x, xb, 4194304);
  cvt_bf16<<<1536, 256, 0, stream>>>(w_qkv, wbq, 393216);
  cvt_bf16<<<512, 256, 0, stream>>>(w_out, wbo, 131072);
  gemm_kvfold<<<1024, 512, 0, stream>>>(xb, wbq, Pp, KsP);
  reduce_kv2<<<dim3(64, 17), 256, 0, stream>>>(Pp, KsP, kvb, ksb);
  gemm_qattn<<<512, 512, 0, stream>>>(xb, wbq, kvb, ksb, attn);
  gemm_out<<<512, 512, 0, stream>>>(attn, wbo, (float*)O);
}